// Round 1
// baseline (314.494 us; speedup 1.0000x reference)
//
#include <hip/hip_runtime.h>
#include <math.h>

#define B_SZ 16384
#define C_SZ 2048
#define D_SZ 128
#define MAXP 256

// ---- workspace layout (bytes) ----
// 0        : pos_count[C]   int     (8192)
// 8192     : acc[2]         float   (8)     [loss_sum, valid_count]
// 8448     : pos_list[C*MAXP] int   (2 MB)
// 2105600  : pn[C*D]        f32     (1 MB)
// 3154176  : en[C*D]        f32     (1 MB)
// 4202752  : class_sim[C*C] f32     (16 MB)
// 20979968 : all_cosine[C*C]f32     (16 MB)
// total ~36 MB

// Scan targets (coalesced float4), build per-class positive-row lists.
__global__ __launch_bounds__(256) void k_scan(const float* __restrict__ targets,
                                              int* __restrict__ pos_count,
                                              int* __restrict__ pos_list) {
    int tid = blockIdx.x * blockDim.x + threadIdx.x;
    int total = (B_SZ * C_SZ) >> 2;
    int stride = gridDim.x * blockDim.x;
    for (int v = tid; v < total; v += stride) {
        float4 t = ((const float4*)targets)[v];
        if (t.x != 0.f || t.y != 0.f || t.z != 0.f || t.w != 0.f) {
            int e0 = v << 2;
            int b = e0 >> 11;        // / C_SZ
            int c0 = e0 & (C_SZ - 1);
            float vals[4] = {t.x, t.y, t.z, t.w};
#pragma unroll
            for (int q = 0; q < 4; ++q) {
                if (vals[q] != 0.f) {
                    int c = c0 + q;
                    int slot = atomicAdd(&pos_count[c], 1);
                    if (slot < MAXP) pos_list[c * MAXP + slot] = b;
                }
            }
        }
    }
}

// Per-class masked mean pool + L2 normalize -> pn
__global__ __launch_bounds__(128) void k_pool(const float* __restrict__ output,
                                              const int* __restrict__ pos_count,
                                              const int* __restrict__ pos_list,
                                              float* __restrict__ pn) {
    int c = blockIdx.x;
    int d = threadIdx.x;
    int n = pos_count[c];
    if (n > MAXP) n = MAXP;
    float acc = 0.f, cnt = 0.f;
    for (int k = 0; k < n; ++k) {
        int b = pos_list[c * MAXP + k];
        float v = output[b * D_SZ + d];
        acc += v;
        cnt += (v != 0.f) ? 1.f : 0.f;
    }
    float pooled = acc / (cnt + 1e-9f);
    float sq = pooled * pooled;
#pragma unroll
    for (int off = 32; off >= 1; off >>= 1) sq += __shfl_xor(sq, off);
    __shared__ float s_w[2];
    if ((d & 63) == 0) s_w[d >> 6] = sq;
    __syncthreads();
    float tot = s_w[0] + s_w[1];
    pn[c * D_SZ + d] = pooled * rsqrtf(tot + 1e-12f);
}

// L2 normalize class_emb -> en
__global__ __launch_bounds__(128) void k_norm(const float* __restrict__ emb,
                                              float* __restrict__ en) {
    int c = blockIdx.x;
    int d = threadIdx.x;
    float v = emb[c * D_SZ + d];
    float sq = v * v;
#pragma unroll
    for (int off = 32; off >= 1; off >>= 1) sq += __shfl_xor(sq, off);
    __shared__ float s_w[2];
    if ((d & 63) == 0) s_w[d >> 6] = sq;
    __syncthreads();
    float tot = s_w[0] + s_w[1];
    en[c * D_SZ + d] = v * rsqrtf(tot + 1e-12f);
}

// C[r,c] = sum_k A[r,k]*Bm[c,k]   (A,Bm: [C_SZ, D_SZ] row-major, out [C_SZ,C_SZ])
// 64x64 tile per block, 256 threads, 4x4 per thread, K=128 staged transposed in LDS.
__global__ __launch_bounds__(256) void k_gemm_nt(const float* __restrict__ A,
                                                 const float* __restrict__ Bm,
                                                 float* __restrict__ Cm) {
    __shared__ float As[D_SZ][68];
    __shared__ float Bs[D_SZ][68];
    int tid = threadIdx.x;
    int rb = blockIdx.y << 6, cb = blockIdx.x << 6;
    for (int t = tid; t < 64 * 32; t += 256) {
        int r = t >> 5;            // 0..63
        int k4 = (t & 31) << 2;    // 0..124
        float4 va = *(const float4*)&A[(rb + r) * D_SZ + k4];
        As[k4 + 0][r] = va.x; As[k4 + 1][r] = va.y;
        As[k4 + 2][r] = va.z; As[k4 + 3][r] = va.w;
        float4 vb = *(const float4*)&Bm[(cb + r) * D_SZ + k4];
        Bs[k4 + 0][r] = vb.x; Bs[k4 + 1][r] = vb.y;
        Bs[k4 + 2][r] = vb.z; Bs[k4 + 3][r] = vb.w;
    }
    __syncthreads();
    int tx = tid & 15, ty = tid >> 4;
    float acc[4][4] = {};
#pragma unroll 8
    for (int k = 0; k < D_SZ; ++k) {
        float4 a = *(const float4*)&As[k][ty << 2];
        float4 b = *(const float4*)&Bs[k][tx << 2];
        float av[4] = {a.x, a.y, a.z, a.w};
        float bv[4] = {b.x, b.y, b.z, b.w};
#pragma unroll
        for (int i = 0; i < 4; ++i)
#pragma unroll
            for (int j = 0; j < 4; ++j) acc[i][j] += av[i] * bv[j];
    }
#pragma unroll
    for (int i = 0; i < 4; ++i) {
        float4 o = {acc[i][0], acc[i][1], acc[i][2], acc[i][3]};
        *(float4*)&Cm[(rb + (ty << 2) + i) * C_SZ + cb + (tx << 2)] = o;
    }
}

// Per-row: bitonic stable argsort of class_sim -> ranks -> discounted logits ->
// log_softmax -> diagonal -> accumulate loss.
__global__ __launch_bounds__(256) void k_rank_softmax(const float* __restrict__ sim,
                                                      const float* __restrict__ cosm,
                                                      const int* __restrict__ pos_count,
                                                      const float* __restrict__ tempPtr,
                                                      float* __restrict__ acc) {
    int i = blockIdx.x;
    if (pos_count[i] == 0) return;   // invalid class: contributes nothing
    __shared__ float s_f[C_SZ];
    __shared__ int s_i[C_SZ];
    __shared__ int s_r[C_SZ];
    __shared__ float s_red[4];
    int tid = threadIdx.x;
    const int T = 256;
    for (int p = tid; p < C_SZ; p += T) { s_f[p] = sim[i * C_SZ + p]; s_i[p] = p; }
    __syncthreads();
    // bitonic sort ascending by (value, index) — reproduces stable argsort
    for (int k = 2; k <= C_SZ; k <<= 1) {
        for (int j = k >> 1; j > 0; j >>= 1) {
            for (int p = tid; p < C_SZ; p += T) {
                int q = p ^ j;
                if (q > p) {
                    float fa = s_f[p], fb = s_f[q];
                    int ia = s_i[p], ib = s_i[q];
                    bool agtb = (fa > fb) || (fa == fb && ia > ib);
                    bool up = ((p & k) == 0);
                    if (agtb == up) {
                        s_f[p] = fb; s_f[q] = fa;
                        s_i[p] = ib; s_i[q] = ia;
                    }
                }
            }
            __syncthreads();
        }
    }
    // rank[orig_idx] = sorted position
    for (int p = tid; p < C_SZ; p += T) s_r[s_i[p]] = p;
    __syncthreads();
    float temp = tempPtr[0];
    float lmax = -3.4e38f;
    for (int p = tid; p < C_SZ; p += T) {
        float lg = cosm[i * C_SZ + p] / (temp * logf((float)s_r[p] + 2.0f));
        s_f[p] = lg;
        lmax = fmaxf(lmax, lg);
    }
#pragma unroll
    for (int off = 32; off >= 1; off >>= 1) lmax = fmaxf(lmax, __shfl_xor(lmax, off));
    if ((tid & 63) == 0) s_red[tid >> 6] = lmax;
    __syncthreads();
    float m = fmaxf(fmaxf(s_red[0], s_red[1]), fmaxf(s_red[2], s_red[3]));
    float lsum = 0.f;
    for (int p = tid; p < C_SZ; p += T) lsum += expf(s_f[p] - m);
#pragma unroll
    for (int off = 32; off >= 1; off >>= 1) lsum += __shfl_xor(lsum, off);
    __syncthreads();   // protect s_red before reuse
    if ((tid & 63) == 0) s_red[tid >> 6] = lsum;
    __syncthreads();
    if (tid == 0) {
        float tot = s_red[0] + s_red[1] + s_red[2] + s_red[3];
        float pos_lp = s_f[i] - m - logf(tot);
        atomicAdd(&acc[0], -pos_lp);
        atomicAdd(&acc[1], 1.0f);
    }
}

__global__ void k_final(const float* __restrict__ acc, float* __restrict__ out) {
    out[0] = acc[0] / fmaxf(acc[1], 1.0f);
}

extern "C" void kernel_launch(void* const* d_in, const int* in_sizes, int n_in,
                              void* d_out, int out_size, void* d_ws, size_t ws_size,
                              hipStream_t stream) {
    const float* output    = (const float*)d_in[0];
    const float* class_emb = (const float*)d_in[1];
    const float* targets   = (const float*)d_in[2];
    const float* tempPtr   = (const float*)d_in[3];
    float* out = (float*)d_out;
    char* ws = (char*)d_ws;

    int*   pos_count = (int*)(ws + 0);
    float* acc       = (float*)(ws + 8192);
    int*   pos_list  = (int*)(ws + 8448);
    float* pn        = (float*)(ws + 2105600);
    float* en        = (float*)(ws + 3154176);
    float* sim       = (float*)(ws + 4202752);
    float* cosm      = (float*)(ws + 20979968);

    hipMemsetAsync(ws, 0, 8448, stream);  // pos_count + acc

    k_scan<<<4096, 256, 0, stream>>>(targets, pos_count, pos_list);
    k_pool<<<C_SZ, 128, 0, stream>>>(output, pos_count, pos_list, pn);
    k_norm<<<C_SZ, 128, 0, stream>>>(class_emb, en);
    dim3 g(C_SZ / 64, C_SZ / 64);
    k_gemm_nt<<<g, 256, 0, stream>>>(en, en, sim);
    k_gemm_nt<<<g, 256, 0, stream>>>(pn, en, cosm);
    k_rank_softmax<<<C_SZ, 256, 0, stream>>>(sim, cosm, pos_count, tempPtr, acc);
    k_final<<<1, 1, 0, stream>>>(acc, out);
}

// Round 2
// 192.090 us; speedup vs baseline: 1.6372x; 1.6372x over previous
//
#include <hip/hip_runtime.h>
#include <math.h>

#define B_SZ 16384
#define C_SZ 2048
#define D_SZ 128
#define MAXP 256

// ---- workspace layout (bytes) ----
// 0        : pos_count[C]     int   (8192)
// 8192     : acc[2]           float (8)   [loss_sum, valid_count]
// 8448     : pos_list[C*MAXP] int   (2 MB)  -> ends 2,105,600
// 2105600  : pn[C*D]          f32   (1 MB)  -> ends 3,154,176
// 3154176  : en[C*D]          f32   (1 MB)  -> ends 4,202,752
// 4202752  : tab[C]           f32   (8 KB)  -> ends 4,210,944
// 4210944  : sim[C*C]         f32   (16 MB) -> ends 20,988,160
// 20988160 : cosm[C*C]        f32   (16 MB) -> ends 37,765,376

__device__ __forceinline__ int ph_swz(int p) { return p ^ ((p >> 6) << 1); }

// Scan targets (coalesced float4), build per-class positive-row lists.
__global__ __launch_bounds__(256) void k_scan(const float* __restrict__ targets,
                                              int* __restrict__ pos_count,
                                              int* __restrict__ pos_list) {
    int tid = blockIdx.x * blockDim.x + threadIdx.x;
    int total = (B_SZ * C_SZ) >> 2;
    int stride = gridDim.x * blockDim.x;
    for (int v = tid; v < total; v += stride) {
        float4 t = ((const float4*)targets)[v];
        if (t.x != 0.f || t.y != 0.f || t.z != 0.f || t.w != 0.f) {
            int e0 = v << 2;
            int b = e0 >> 11;        // / C_SZ
            int c0 = e0 & (C_SZ - 1);
            float vals[4] = {t.x, t.y, t.z, t.w};
#pragma unroll
            for (int q = 0; q < 4; ++q) {
                if (vals[q] != 0.f) {
                    int c = c0 + q;
                    int slot = atomicAdd(&pos_count[c], 1);
                    if (slot < MAXP) pos_list[c * MAXP + slot] = b;
                }
            }
        }
    }
}

// Per-class masked mean pool + L2 normalize -> pn
__global__ __launch_bounds__(128) void k_pool(const float* __restrict__ output,
                                              const int* __restrict__ pos_count,
                                              const int* __restrict__ pos_list,
                                              float* __restrict__ pn) {
    int c = blockIdx.x;
    int d = threadIdx.x;
    int n = pos_count[c];
    if (n > MAXP) n = MAXP;
    float acc = 0.f, cnt = 0.f;
    for (int k = 0; k < n; ++k) {
        int b = pos_list[c * MAXP + k];
        float v = output[b * D_SZ + d];
        acc += v;
        cnt += (v != 0.f) ? 1.f : 0.f;
    }
    float pooled = acc / (cnt + 1e-9f);
    float sq = pooled * pooled;
#pragma unroll
    for (int off = 32; off >= 1; off >>= 1) sq += __shfl_xor(sq, off);
    __shared__ float s_w[2];
    if ((d & 63) == 0) s_w[d >> 6] = sq;
    __syncthreads();
    float tot = s_w[0] + s_w[1];
    pn[c * D_SZ + d] = pooled * rsqrtf(tot + 1e-12f);
}

// L2 normalize class_emb -> en
__global__ __launch_bounds__(128) void k_norm(const float* __restrict__ emb,
                                              float* __restrict__ en) {
    int c = blockIdx.x;
    int d = threadIdx.x;
    float v = emb[c * D_SZ + d];
    float sq = v * v;
#pragma unroll
    for (int off = 32; off >= 1; off >>= 1) sq += __shfl_xor(sq, off);
    __shared__ float s_w[2];
    if ((d & 63) == 0) s_w[d >> 6] = sq;
    __syncthreads();
    float tot = s_w[0] + s_w[1];
    en[c * D_SZ + d] = v * rsqrtf(tot + 1e-12f);
}

// discount table: tab[r] = 1 / (temp * log(r+2))
__global__ void k_tab(const float* __restrict__ tempPtr, float* __restrict__ tab) {
    int r = blockIdx.x * blockDim.x + threadIdx.x;
    if (r < C_SZ) tab[r] = 1.0f / (tempPtr[0] * logf((float)r + 2.0f));
}

// C[r,c] = sum_k A[r,k]*Bm[c,k]   (A,Bm: [C_SZ, D_SZ] row-major, out [C_SZ,C_SZ])
__global__ __launch_bounds__(256) void k_gemm_nt(const float* __restrict__ A,
                                                 const float* __restrict__ Bm,
                                                 float* __restrict__ Cm) {
    __shared__ float As[D_SZ][68];
    __shared__ float Bs[D_SZ][68];
    int tid = threadIdx.x;
    int rb = blockIdx.y << 6, cb = blockIdx.x << 6;
    for (int t = tid; t < 64 * 32; t += 256) {
        int r = t >> 5;            // 0..63
        int k4 = (t & 31) << 2;    // 0..124
        float4 va = *(const float4*)&A[(rb + r) * D_SZ + k4];
        As[k4 + 0][r] = va.x; As[k4 + 1][r] = va.y;
        As[k4 + 2][r] = va.z; As[k4 + 3][r] = va.w;
        float4 vb = *(const float4*)&Bm[(cb + r) * D_SZ + k4];
        Bs[k4 + 0][r] = vb.x; Bs[k4 + 1][r] = vb.y;
        Bs[k4 + 2][r] = vb.z; Bs[k4 + 3][r] = vb.w;
    }
    __syncthreads();
    int tx = tid & 15, ty = tid >> 4;
    float acc[4][4] = {};
#pragma unroll 8
    for (int k = 0; k < D_SZ; ++k) {
        float4 a = *(const float4*)&As[k][ty << 2];
        float4 b = *(const float4*)&Bs[k][tx << 2];
        float av[4] = {a.x, a.y, a.z, a.w};
        float bv[4] = {b.x, b.y, b.z, b.w};
#pragma unroll
        for (int i = 0; i < 4; ++i)
#pragma unroll
            for (int j = 0; j < 4; ++j) acc[i][j] += av[i] * bv[j];
    }
#pragma unroll
    for (int i = 0; i < 4; ++i) {
        float4 o = {acc[i][0], acc[i][1], acc[i][2], acc[i][3]};
        *(float4*)&Cm[(rb + (ty << 2) + i) * C_SZ + cb + (tx << 2)] = o;
    }
}

// Per-row: stable LSD radix argsort (8x4-bit) -> ranks -> discounted logits ->
// log_softmax -> diagonal -> accumulate loss.
__global__ __launch_bounds__(256) void k_rank_softmax(const float* __restrict__ sim,
                                                      const float* __restrict__ cosm,
                                                      const int* __restrict__ pos_count,
                                                      const float* __restrict__ tab,
                                                      float* __restrict__ acc) {
    int i = blockIdx.x;
    if (pos_count[i] == 0) return;
    __shared__ unsigned s_k[2][C_SZ];        // 16 KB ping-pong keys
    __shared__ unsigned short s_v[2][C_SZ];  // 8 KB ping-pong indices
    __shared__ unsigned short s_h[4096];     // 8 KB hist / ranks
    __shared__ int s_wt[4];
    __shared__ float s_red[4];
    __shared__ float s_diag;
    const int tid = threadIdx.x;
    const int lane = tid & 63;
    const int w = tid >> 6;
    const int base = tid << 3;   // 8 contiguous elements per thread

    // ---- load row, transform to order-preserving uint keys ----
    {
        const float4* sp = (const float4*)&sim[i * C_SZ + base];
        float4 a = sp[0], b = sp[1];
        float xs[8] = {a.x, a.y, a.z, a.w, b.x, b.y, b.z, b.w};
#pragma unroll
        for (int e = 0; e < 8; ++e) {
            unsigned u = __float_as_uint(xs[e]);
            u = (u & 0x80000000u) ? ~u : (u | 0x80000000u);
            s_k[0][base + e] = u;
            s_v[0][base + e] = (unsigned short)(base + e);
        }
    }
    __syncthreads();

    int cur = 0;
#pragma unroll 1
    for (int pass = 0; pass < 8; ++pass) {
        const int shift = pass << 2;
        // read own chunk (vectorized LDS reads)
        uint4 k0 = *(const uint4*)&s_k[cur][base];
        uint4 k1 = *(const uint4*)&s_k[cur][base + 4];
        unsigned kl[8] = {k0.x, k0.y, k0.z, k0.w, k1.x, k1.y, k1.z, k1.w};
        uint4 vr = *(const uint4*)&s_v[cur][base];
        int vl[8] = {(int)(vr.x & 0xFFFF), (int)(vr.x >> 16),
                     (int)(vr.y & 0xFFFF), (int)(vr.y >> 16),
                     (int)(vr.z & 0xFFFF), (int)(vr.z >> 16),
                     (int)(vr.w & 0xFFFF), (int)(vr.w >> 16)};
        int dig[8];
        unsigned long long pc = 0ull;   // 16 x 4-bit packed per-bucket counts
#pragma unroll
        for (int e = 0; e < 8; ++e) {
            dig[e] = (int)((kl[e] >> shift) & 15u);
            pc += 1ull << (dig[e] << 2);
        }
        // hist write: entry (b, tid) at swizzled pos b*256+tid
#pragma unroll
        for (int b = 0; b < 16; ++b) {
            int p = (b << 8) + tid;
            s_h[ph_swz(p)] = (unsigned short)((pc >> (b << 2)) & 15ull);
        }
        __syncthreads();
        // exclusive scan of 4096 entries; thread scans 16 contiguous positions
        int vals[16];
        int sum = 0;
#pragma unroll
        for (int j = 0; j < 8; ++j) {
            int p = (tid << 4) + (j << 1);
            unsigned pr = ((unsigned*)s_h)[ph_swz(p) >> 1];
            int v0 = (int)(pr & 0xFFFF), v1 = (int)(pr >> 16);
            vals[2 * j] = sum; sum += v0;
            vals[2 * j + 1] = sum; sum += v1;
        }
        int incl = sum;
#pragma unroll
        for (int off = 1; off < 64; off <<= 1) {
            int o = __shfl_up(incl, off);
            if (lane >= off) incl += o;
        }
        if (lane == 63) s_wt[w] = incl;
        __syncthreads();
        int wbase = 0;
#pragma unroll
        for (int ww = 0; ww < 4; ++ww) wbase += (ww < w) ? s_wt[ww] : 0;
        int ebase = wbase + incl - sum;
#pragma unroll
        for (int j = 0; j < 8; ++j) {
            int p = (tid << 4) + (j << 1);
            unsigned packed = (unsigned)(vals[2 * j] + ebase) |
                              ((unsigned)(vals[2 * j + 1] + ebase) << 16);
            ((unsigned*)s_h)[ph_swz(p) >> 1] = packed;
        }
        __syncthreads();
        // stable scatter
        const int nxt = cur ^ 1;
        unsigned long long run = 0ull;
#pragma unroll
        for (int e = 0; e < 8; ++e) {
            int sh2 = dig[e] << 2;
            int prior = (int)((run >> sh2) & 15ull);
            run += 1ull << sh2;
            int gb = (int)s_h[ph_swz((dig[e] << 8) + tid)];
            int dst = gb + prior;
            s_k[nxt][dst] = kl[e];
            s_v[nxt][dst] = (unsigned short)vl[e];
        }
        __syncthreads();
        cur = nxt;
    }
    // cur == 0: sorted (key, idx) in s_k[0]/s_v[0].
    // ranks: s_r[orig_idx] = sorted position (plain layout, reuse s_h)
    unsigned short* s_r = s_h;
#pragma unroll
    for (int e = 0; e < 8; ++e) {
        int p = base + e;
        s_r[s_v[0][p]] = (unsigned short)p;
    }
    // stage discount table into freed ping buffer
    float* s_tab = (float*)s_k[1];
    for (int p = tid; p < C_SZ; p += 256) s_tab[p] = tab[p];
    __syncthreads();

    // logits in registers
    float lg[8];
    float lmax = -3.4e38f;
    {
        const float4* cp = (const float4*)&cosm[i * C_SZ + base];
        float4 a = cp[0], b = cp[1];
        float cs[8] = {a.x, a.y, a.z, a.w, b.x, b.y, b.z, b.w};
        uint4 rr = *(const uint4*)&s_r[base];
        int rv[8] = {(int)(rr.x & 0xFFFF), (int)(rr.x >> 16),
                     (int)(rr.y & 0xFFFF), (int)(rr.y >> 16),
                     (int)(rr.z & 0xFFFF), (int)(rr.z >> 16),
                     (int)(rr.w & 0xFFFF), (int)(rr.w >> 16)};
#pragma unroll
        for (int e = 0; e < 8; ++e) {
            lg[e] = cs[e] * s_tab[rv[e]];
            lmax = fmaxf(lmax, lg[e]);
        }
    }
    // diagonal (register-safe select)
    if ((i >> 3) == tid) {
        int ei = i & 7;
        float dv = lg[0];
#pragma unroll
        for (int e = 1; e < 8; ++e) dv = (ei == e) ? lg[e] : dv;
        s_diag = dv;
    }
#pragma unroll
    for (int off = 1; off < 64; off <<= 1) lmax = fmaxf(lmax, __shfl_xor(lmax, off));
    if (lane == 0) s_red[w] = lmax;
    __syncthreads();
    float m = fmaxf(fmaxf(s_red[0], s_red[1]), fmaxf(s_red[2], s_red[3]));
    float lsum = 0.f;
#pragma unroll
    for (int e = 0; e < 8; ++e) lsum += __expf(lg[e] - m);
#pragma unroll
    for (int off = 1; off < 64; off <<= 1) lsum += __shfl_xor(lsum, off);
    __syncthreads();
    if (lane == 0) s_red[w] = lsum;
    __syncthreads();
    if (tid == 0) {
        float tot = s_red[0] + s_red[1] + s_red[2] + s_red[3];
        float pos_lp = s_diag - m - logf(tot);
        atomicAdd(&acc[0], -pos_lp);
        atomicAdd(&acc[1], 1.0f);
    }
}

__global__ void k_final(const float* __restrict__ acc, float* __restrict__ out) {
    out[0] = acc[0] / fmaxf(acc[1], 1.0f);
}

extern "C" void kernel_launch(void* const* d_in, const int* in_sizes, int n_in,
                              void* d_out, int out_size, void* d_ws, size_t ws_size,
                              hipStream_t stream) {
    const float* output    = (const float*)d_in[0];
    const float* class_emb = (const float*)d_in[1];
    const float* targets   = (const float*)d_in[2];
    const float* tempPtr   = (const float*)d_in[3];
    float* out = (float*)d_out;
    char* ws = (char*)d_ws;

    int*   pos_count = (int*)(ws + 0);
    float* acc       = (float*)(ws + 8192);
    int*   pos_list  = (int*)(ws + 8448);
    float* pn        = (float*)(ws + 2105600);
    float* en        = (float*)(ws + 3154176);
    float* tab       = (float*)(ws + 4202752);
    float* sim       = (float*)(ws + 4210944);
    float* cosm      = (float*)(ws + 20988160);

    hipMemsetAsync(ws, 0, 8448, stream);  // pos_count + acc

    k_scan<<<4096, 256, 0, stream>>>(targets, pos_count, pos_list);
    k_pool<<<C_SZ, 128, 0, stream>>>(output, pos_count, pos_list, pn);
    k_norm<<<C_SZ, 128, 0, stream>>>(class_emb, en);
    k_tab<<<C_SZ / 256, 256, 0, stream>>>(tempPtr, tab);
    dim3 g(C_SZ / 64, C_SZ / 64);
    k_gemm_nt<<<g, 256, 0, stream>>>(en, en, sim);
    k_gemm_nt<<<g, 256, 0, stream>>>(pn, en, cosm);
    k_rank_softmax<<<C_SZ, 256, 0, stream>>>(sim, cosm, pos_count, tab, acc);
    k_final<<<1, 1, 0, stream>>>(acc, out);
}

// Round 3
// 154.351 us; speedup vs baseline: 2.0375x; 1.2445x over previous
//
#include <hip/hip_runtime.h>
#include <hip/hip_bf16.h>
#include <math.h>

#define B_SZ 16384
#define C_SZ 2048
#define D_SZ 128
#define MAXP 256

typedef float f32x4 __attribute__((ext_vector_type(4)));
typedef short short8 __attribute__((ext_vector_type(8)));

// ---- workspace layout (bytes) ----
// 0        : pos_count[C]     int   (8192)
// 8192     : acc[2]           float (8)
// 8448     : pos_list[C*MAXP] int   (2 MB)   -> 2,105,600
// 2105600  : pnh [C*D] bf16 (512KB) -> 2,629,888
// 2629888  : pnl [C*D] bf16 (512KB) -> 3,154,176
// 3154176  : enh [C*D] bf16 (512KB) -> 3,678,464
// 3678464  : enl [C*D] bf16 (512KB) -> 4,202,752
// 4202752  : tab[C] f32 (8KB)       -> 4,210,944
// 4210944  : sim[C*C] f32 (16MB)    -> 20,988,160
// 20988160 : cosm[C*C] f32 (16MB)   -> 37,765,376

__device__ __forceinline__ int ph_swz(int p) { return p ^ ((p >> 6) << 1); }

__global__ __launch_bounds__(256) void k_scan(const float* __restrict__ targets,
                                              int* __restrict__ pos_count,
                                              int* __restrict__ pos_list) {
    int tid = blockIdx.x * blockDim.x + threadIdx.x;
    int total = (B_SZ * C_SZ) >> 2;
    int stride = gridDim.x * blockDim.x;
    for (int v = tid; v < total; v += stride) {
        float4 t = ((const float4*)targets)[v];
        if (t.x != 0.f || t.y != 0.f || t.z != 0.f || t.w != 0.f) {
            int e0 = v << 2;
            int b = e0 >> 11;
            int c0 = e0 & (C_SZ - 1);
            float vals[4] = {t.x, t.y, t.z, t.w};
#pragma unroll
            for (int q = 0; q < 4; ++q) {
                if (vals[q] != 0.f) {
                    int c = c0 + q;
                    int slot = atomicAdd(&pos_count[c], 1);
                    if (slot < MAXP) pos_list[c * MAXP + slot] = b;
                }
            }
        }
    }
}

// masked mean pool + L2 norm -> split bf16 (hi, lo)
__global__ __launch_bounds__(128) void k_pool(const float* __restrict__ output,
                                              const int* __restrict__ pos_count,
                                              const int* __restrict__ pos_list,
                                              __hip_bfloat16* __restrict__ pnh,
                                              __hip_bfloat16* __restrict__ pnl) {
    int c = blockIdx.x;
    int d = threadIdx.x;
    int n = pos_count[c];
    if (n > MAXP) n = MAXP;
    float acc = 0.f, cnt = 0.f;
    for (int k = 0; k < n; ++k) {
        int b = pos_list[c * MAXP + k];
        float v = output[b * D_SZ + d];
        acc += v;
        cnt += (v != 0.f) ? 1.f : 0.f;
    }
    float pooled = acc / (cnt + 1e-9f);
    float sq = pooled * pooled;
#pragma unroll
    for (int off = 32; off >= 1; off >>= 1) sq += __shfl_xor(sq, off);
    __shared__ float s_w[2];
    if ((d & 63) == 0) s_w[d >> 6] = sq;
    __syncthreads();
    float tot = s_w[0] + s_w[1];
    float vn = pooled * rsqrtf(tot + 1e-12f);
    __hip_bfloat16 h = __float2bfloat16(vn);
    pnh[c * D_SZ + d] = h;
    pnl[c * D_SZ + d] = __float2bfloat16(vn - __bfloat162float(h));
}

// L2 norm class_emb -> split bf16; thread 0 also writes discount table entry
__global__ __launch_bounds__(128) void k_norm(const float* __restrict__ emb,
                                              const float* __restrict__ tempPtr,
                                              __hip_bfloat16* __restrict__ enh,
                                              __hip_bfloat16* __restrict__ enl,
                                              float* __restrict__ tab) {
    int c = blockIdx.x;
    int d = threadIdx.x;
    float v = emb[c * D_SZ + d];
    float sq = v * v;
#pragma unroll
    for (int off = 32; off >= 1; off >>= 1) sq += __shfl_xor(sq, off);
    __shared__ float s_w[2];
    if ((d & 63) == 0) s_w[d >> 6] = sq;
    __syncthreads();
    float tot = s_w[0] + s_w[1];
    float vn = v * rsqrtf(tot + 1e-12f);
    __hip_bfloat16 h = __float2bfloat16(vn);
    enh[c * D_SZ + d] = h;
    enl[c * D_SZ + d] = __float2bfloat16(vn - __bfloat162float(h));
    if (d == 0) tab[c] = 1.0f / (tempPtr[0] * logf((float)c + 2.0f));
}

// C[r,c] = sum_k X[r,k]*Y[c,k] via split-bf16 MFMA (4 cross terms, f32-accurate).
// 64x64 tile, 256 thr (4 waves, 2x2 of 32x32), 64KB dyn LDS, XOR-swizzled rows.
__global__ __launch_bounds__(256) void k_gemm_mfma(const __hip_bfloat16* __restrict__ Ah,
                                                   const __hip_bfloat16* __restrict__ Al,
                                                   const __hip_bfloat16* __restrict__ Bh,
                                                   const __hip_bfloat16* __restrict__ Bl,
                                                   float* __restrict__ Cm) {
    extern __shared__ char smem[];
    char* As = smem;           // 64 rows * 512B: kbyte 0..255 = hi, 256..511 = lo
    char* Bs = smem + 32768;
    const int tid = threadIdx.x;
    const int rb = blockIdx.y << 6, cb = blockIdx.x << 6;
    {
        int r = tid >> 2;
        int c0 = (tid & 3) << 5;
        int sw = (r & 7) << 4;
#pragma unroll
        for (int j = 0; j < 4; ++j) {
            int c = c0 + (j << 3);
            uint4 vh = *(const uint4*)&Ah[(rb + r) * D_SZ + c];
            *(uint4*)(As + r * 512 + ((2 * c) ^ sw)) = vh;
            uint4 vl = *(const uint4*)&Al[(rb + r) * D_SZ + c];
            *(uint4*)(As + r * 512 + ((512 + 2 * c) ^ sw) - 256) = vl;  // 256+2c, keep XOR in low bits
            uint4 wh = *(const uint4*)&Bh[(cb + r) * D_SZ + c];
            *(uint4*)(Bs + r * 512 + ((2 * c) ^ sw)) = wh;
            uint4 wl = *(const uint4*)&Bl[(cb + r) * D_SZ + c];
            *(uint4*)(Bs + r * 512 + ((512 + 2 * c) ^ sw) - 256) = wl;
        }
    }
    __syncthreads();
    const int w = tid >> 6, lane = tid & 63;
    const int wr = (w >> 1) << 5;
    const int wc = (w & 1) << 5;
    const int lrow = lane & 15;
    const int lk = (lane >> 4) << 4;   // byte offset: (lane>>4)*8 bf16
    int ar0 = wr + lrow, ar1 = wr + 16 + lrow;
    int br0 = wc + lrow, br1 = wc + 16 + lrow;
    const char* pa0 = As + ar0 * 512; const int swa0 = (ar0 & 7) << 4;
    const char* pa1 = As + ar1 * 512; const int swa1 = (ar1 & 7) << 4;
    const char* pb0 = Bs + br0 * 512; const int swb0 = (br0 & 7) << 4;
    const char* pb1 = Bs + br1 * 512; const int swb1 = (br1 & 7) << 4;
    f32x4 acc00 = {0.f, 0.f, 0.f, 0.f};
    f32x4 acc01 = acc00, acc10 = acc00, acc11 = acc00;
#pragma unroll
    for (int term = 0; term < 4; ++term) {
        const int ao = (term >> 1) << 8;   // A: hi,hi,lo,lo
        const int bo = (term & 1) << 8;    // B: hi,lo,hi,lo
#pragma unroll
        for (int kk = 0; kk < 4; ++kk) {
            const int ka = ao + (kk << 6) + lk;
            const int kb = bo + (kk << 6) + lk;
            short8 a0 = *(const short8*)(pa0 + ((ka & 0x100) | ((ka & 0xFF) ^ swa0)));
            short8 a1 = *(const short8*)(pa1 + ((ka & 0x100) | ((ka & 0xFF) ^ swa1)));
            short8 b0 = *(const short8*)(pb0 + ((kb & 0x100) | ((kb & 0xFF) ^ swb0)));
            short8 b1 = *(const short8*)(pb1 + ((kb & 0x100) | ((kb & 0xFF) ^ swb1)));
            acc00 = __builtin_amdgcn_mfma_f32_16x16x32_bf16(a0, b0, acc00, 0, 0, 0);
            acc01 = __builtin_amdgcn_mfma_f32_16x16x32_bf16(a0, b1, acc01, 0, 0, 0);
            acc10 = __builtin_amdgcn_mfma_f32_16x16x32_bf16(a1, b0, acc10, 0, 0, 0);
            acc11 = __builtin_amdgcn_mfma_f32_16x16x32_bf16(a1, b1, acc11, 0, 0, 0);
        }
    }
    const int crow = rb + wr + ((lane >> 4) << 2);
    const int ccol = cb + wc + lrow;
#pragma unroll
    for (int r = 0; r < 4; ++r) {
        Cm[(crow + r) * C_SZ + ccol]           = acc00[r];
        Cm[(crow + r) * C_SZ + ccol + 16]      = acc01[r];
        Cm[(crow + 16 + r) * C_SZ + ccol]      = acc10[r];
        Cm[(crow + 16 + r) * C_SZ + ccol + 16] = acc11[r];
    }
}

// Per-row stable LSD radix argsort (8x4-bit, in-place scatter) -> ranks ->
// discounted logits -> log_softmax -> diagonal -> loss accumulate.
__global__ __launch_bounds__(256) void k_rank_softmax(const float* __restrict__ sim,
                                                      const float* __restrict__ cosm,
                                                      const int* __restrict__ pos_count,
                                                      const float* __restrict__ tab,
                                                      float* __restrict__ acc) {
    int i = blockIdx.x;
    if (pos_count[i] == 0) return;
    __shared__ unsigned s_k[C_SZ];           // 8 KB keys (in-place)
    __shared__ unsigned short s_v[C_SZ];     // 4 KB indices / ranks
    __shared__ unsigned short s_h[4096];     // 8 KB hist
    __shared__ int s_wt[4];
    __shared__ float s_red[4];
    __shared__ float s_diag;
    const int tid = threadIdx.x;
    const int lane = tid & 63;
    const int w = tid >> 6;
    const int base = tid << 3;

    {
        const float4* sp = (const float4*)&sim[i * C_SZ + base];
        float4 a = sp[0], b = sp[1];
        float xs[8] = {a.x, a.y, a.z, a.w, b.x, b.y, b.z, b.w};
#pragma unroll
        for (int e = 0; e < 8; ++e) {
            unsigned u = __float_as_uint(xs[e]);
            u = (u & 0x80000000u) ? ~u : (u | 0x80000000u);
            s_k[base + e] = u;
            s_v[base + e] = (unsigned short)(base + e);
        }
    }
    __syncthreads();

#pragma unroll 1
    for (int pass = 0; pass < 8; ++pass) {
        const int shift = pass << 2;
        uint4 k0 = *(const uint4*)&s_k[base];
        uint4 k1 = *(const uint4*)&s_k[base + 4];
        unsigned kl[8] = {k0.x, k0.y, k0.z, k0.w, k1.x, k1.y, k1.z, k1.w};
        uint4 vr = *(const uint4*)&s_v[base];
        int vl[8] = {(int)(vr.x & 0xFFFF), (int)(vr.x >> 16),
                     (int)(vr.y & 0xFFFF), (int)(vr.y >> 16),
                     (int)(vr.z & 0xFFFF), (int)(vr.z >> 16),
                     (int)(vr.w & 0xFFFF), (int)(vr.w >> 16)};
        int dig[8];
        unsigned long long pc = 0ull;
#pragma unroll
        for (int e = 0; e < 8; ++e) {
            dig[e] = (int)((kl[e] >> shift) & 15u);
            pc += 1ull << (dig[e] << 2);
        }
#pragma unroll
        for (int b = 0; b < 16; ++b) {
            int p = (b << 8) + tid;
            s_h[ph_swz(p)] = (unsigned short)((pc >> (b << 2)) & 15ull);
        }
        __syncthreads();
        int vals[16];
        int sum = 0;
#pragma unroll
        for (int j = 0; j < 8; ++j) {
            int p = (tid << 4) + (j << 1);
            unsigned pr = ((unsigned*)s_h)[ph_swz(p) >> 1];
            int v0 = (int)(pr & 0xFFFF), v1 = (int)(pr >> 16);
            vals[2 * j] = sum; sum += v0;
            vals[2 * j + 1] = sum; sum += v1;
        }
        int incl = sum;
#pragma unroll
        for (int off = 1; off < 64; off <<= 1) {
            int o = __shfl_up(incl, off);
            if (lane >= off) incl += o;
        }
        if (lane == 63) s_wt[w] = incl;
        __syncthreads();
        int wbase = 0;
#pragma unroll
        for (int ww = 0; ww < 4; ++ww) wbase += (ww < w) ? s_wt[ww] : 0;
        int ebase = wbase + incl - sum;
#pragma unroll
        for (int j = 0; j < 8; ++j) {
            int p = (tid << 4) + (j << 1);
            unsigned packed = (unsigned)(vals[2 * j] + ebase) |
                              ((unsigned)(vals[2 * j + 1] + ebase) << 16);
            ((unsigned*)s_h)[ph_swz(p) >> 1] = packed;
        }
        __syncthreads();
        unsigned long long run = 0ull;
#pragma unroll
        for (int e = 0; e < 8; ++e) {
            int sh2 = dig[e] << 2;
            int prior = (int)((run >> sh2) & 15ull);
            run += 1ull << sh2;
            int gb = (int)s_h[ph_swz((dig[e] << 8) + tid)];
            int dst = gb + prior;
            s_k[dst] = kl[e];
            s_v[dst] = (unsigned short)vl[e];
        }
        __syncthreads();
    }
    // sorted (key,idx). ranks into s_v in place: read own sorted idx, barrier, scatter.
    uint4 vr = *(const uint4*)&s_v[base];
    int sv[8] = {(int)(vr.x & 0xFFFF), (int)(vr.x >> 16),
                 (int)(vr.y & 0xFFFF), (int)(vr.y >> 16),
                 (int)(vr.z & 0xFFFF), (int)(vr.z >> 16),
                 (int)(vr.w & 0xFFFF), (int)(vr.w >> 16)};
    __syncthreads();
#pragma unroll
    for (int e = 0; e < 8; ++e) s_v[sv[e]] = (unsigned short)(base + e);
    // keys no longer needed: stage discount table there
    float* s_tab = (float*)s_k;
    for (int p = tid; p < C_SZ; p += 256) s_tab[p] = tab[p];
    __syncthreads();

    float lg[8];
    float lmax = -3.4e38f;
    {
        const float4* cp = (const float4*)&cosm[i * C_SZ + base];
        float4 a = cp[0], b = cp[1];
        float cs[8] = {a.x, a.y, a.z, a.w, b.x, b.y, b.z, b.w};
        uint4 rr = *(const uint4*)&s_v[base];
        int rv[8] = {(int)(rr.x & 0xFFFF), (int)(rr.x >> 16),
                     (int)(rr.y & 0xFFFF), (int)(rr.y >> 16),
                     (int)(rr.z & 0xFFFF), (int)(rr.z >> 16),
                     (int)(rr.w & 0xFFFF), (int)(rr.w >> 16)};
#pragma unroll
        for (int e = 0; e < 8; ++e) {
            lg[e] = cs[e] * s_tab[rv[e]];
            lmax = fmaxf(lmax, lg[e]);
        }
    }
    if ((i >> 3) == tid) {
        int ei = i & 7;
        float dv = lg[0];
#pragma unroll
        for (int e = 1; e < 8; ++e) dv = (ei == e) ? lg[e] : dv;
        s_diag = dv;
    }
#pragma unroll
    for (int off = 1; off < 64; off <<= 1) lmax = fmaxf(lmax, __shfl_xor(lmax, off));
    if (lane == 0) s_red[w] = lmax;
    __syncthreads();
    float m = fmaxf(fmaxf(s_red[0], s_red[1]), fmaxf(s_red[2], s_red[3]));
    float lsum = 0.f;
#pragma unroll
    for (int e = 0; e < 8; ++e) lsum += __expf(lg[e] - m);
#pragma unroll
    for (int off = 1; off < 64; off <<= 1) lsum += __shfl_xor(lsum, off);
    __syncthreads();
    if (lane == 0) s_red[w] = lsum;
    __syncthreads();
    if (tid == 0) {
        float tot = s_red[0] + s_red[1] + s_red[2] + s_red[3];
        float pos_lp = s_diag - m - logf(tot);
        atomicAdd(&acc[0], -pos_lp);
        atomicAdd(&acc[1], 1.0f);
    }
}

__global__ void k_final(const float* __restrict__ acc, float* __restrict__ out) {
    out[0] = acc[0] / fmaxf(acc[1], 1.0f);
}

extern "C" void kernel_launch(void* const* d_in, const int* in_sizes, int n_in,
                              void* d_out, int out_size, void* d_ws, size_t ws_size,
                              hipStream_t stream) {
    const float* output    = (const float*)d_in[0];
    const float* class_emb = (const float*)d_in[1];
    const float* targets   = (const float*)d_in[2];
    const float* tempPtr   = (const float*)d_in[3];
    float* out = (float*)d_out;
    char* ws = (char*)d_ws;

    int*   pos_count = (int*)(ws + 0);
    float* acc       = (float*)(ws + 8192);
    int*   pos_list  = (int*)(ws + 8448);
    __hip_bfloat16* pnh = (__hip_bfloat16*)(ws + 2105600);
    __hip_bfloat16* pnl = (__hip_bfloat16*)(ws + 2629888);
    __hip_bfloat16* enh = (__hip_bfloat16*)(ws + 3154176);
    __hip_bfloat16* enl = (__hip_bfloat16*)(ws + 3678464);
    float* tab       = (float*)(ws + 4202752);
    float* sim       = (float*)(ws + 4210944);
    float* cosm      = (float*)(ws + 20988160);

    hipMemsetAsync(ws, 0, 8448, stream);

    k_scan<<<4096, 256, 0, stream>>>(targets, pos_count, pos_list);
    k_pool<<<C_SZ, 128, 0, stream>>>(output, pos_count, pos_list, pnh, pnl);
    k_norm<<<C_SZ, 128, 0, stream>>>(class_emb, tempPtr, enh, enl, tab);
    dim3 g(C_SZ / 64, C_SZ / 64);
    k_gemm_mfma<<<g, 256, 65536, stream>>>(enh, enl, enh, enl, sim);
    k_gemm_mfma<<<g, 256, 65536, stream>>>(pnh, pnl, enh, enl, cosm);
    k_rank_softmax<<<C_SZ, 256, 0, stream>>>(sim, cosm, pos_count, tab, acc);
    k_final<<<1, 1, 0, stream>>>(acc, out);
}

// Round 4
// 140.887 us; speedup vs baseline: 2.2322x; 1.0956x over previous
//
#include <hip/hip_runtime.h>
#include <hip/hip_bf16.h>
#include <math.h>

#define B_SZ 16384
#define C_SZ 2048
#define D_SZ 128
#define MAXP 256

typedef float f32x4 __attribute__((ext_vector_type(4)));
typedef short short8 __attribute__((ext_vector_type(8)));

// ---- workspace layout (bytes) ----
// 0        : pos_count[C]     int   (8192)
// 8192     : acc[2]           float (8)
// 8448     : pos_list[C*MAXP] int   (2 MB)   -> 2,105,600
// 2105600  : pnh [C*D] bf16 (512KB) -> 2,629,888
// 2629888  : pnl [C*D] bf16 (512KB) -> 3,154,176
// 3154176  : enh [C*D] bf16 (512KB) -> 3,678,464
// 3678464  : enl [C*D] bf16 (512KB) -> 4,202,752
// 4202752  : tab[C] f32 (8KB)       -> 4,210,944
// 4210944  : sim[C*C] f32 (16MB)    -> 20,988,160
// 20988160 : cosm[C*C] f32 (16MB)   -> 37,765,376

__global__ __launch_bounds__(256) void k_scan(const float* __restrict__ targets,
                                              int* __restrict__ pos_count,
                                              int* __restrict__ pos_list) {
    int tid = blockIdx.x * blockDim.x + threadIdx.x;
    int total = (B_SZ * C_SZ) >> 2;
    int stride = gridDim.x * blockDim.x;
    for (int v = tid; v < total; v += stride) {
        float4 t = ((const float4*)targets)[v];
        if (t.x != 0.f || t.y != 0.f || t.z != 0.f || t.w != 0.f) {
            int e0 = v << 2;
            int b = e0 >> 11;
            int c0 = e0 & (C_SZ - 1);
            float vals[4] = {t.x, t.y, t.z, t.w};
#pragma unroll
            for (int q = 0; q < 4; ++q) {
                if (vals[q] != 0.f) {
                    int c = c0 + q;
                    int slot = atomicAdd(&pos_count[c], 1);
                    if (slot < MAXP) pos_list[c * MAXP + slot] = b;
                }
            }
        }
    }
}

// blocks 0..2047: L2-normalize class_emb -> en(h,l) + tab; blocks 2048..4095: pool -> pn(h,l)
__global__ __launch_bounds__(128) void k_poolnorm(const float* __restrict__ output,
                                                  const float* __restrict__ class_emb,
                                                  const float* __restrict__ tempPtr,
                                                  const int* __restrict__ pos_count,
                                                  const int* __restrict__ pos_list,
                                                  __hip_bfloat16* __restrict__ pnh,
                                                  __hip_bfloat16* __restrict__ pnl,
                                                  __hip_bfloat16* __restrict__ enh,
                                                  __hip_bfloat16* __restrict__ enl,
                                                  float* __restrict__ tab) {
    int d = threadIdx.x;
    __shared__ float s_w[2];
    if (blockIdx.x < C_SZ) {
        int c = blockIdx.x;
        float v = class_emb[c * D_SZ + d];
        float sq = v * v;
#pragma unroll
        for (int off = 32; off >= 1; off >>= 1) sq += __shfl_xor(sq, off);
        if ((d & 63) == 0) s_w[d >> 6] = sq;
        __syncthreads();
        float tot = s_w[0] + s_w[1];
        float vn = v * rsqrtf(tot + 1e-12f);
        __hip_bfloat16 h = __float2bfloat16(vn);
        enh[c * D_SZ + d] = h;
        enl[c * D_SZ + d] = __float2bfloat16(vn - __bfloat162float(h));
        if (d == 0) tab[c] = 1.0f / (tempPtr[0] * logf((float)c + 2.0f));
    } else {
        int c = blockIdx.x - C_SZ;
        int n = pos_count[c];
        if (n > MAXP) n = MAXP;
        float acc = 0.f, cnt = 0.f;
        for (int k = 0; k < n; ++k) {
            int b = pos_list[c * MAXP + k];
            float v = output[b * D_SZ + d];
            acc += v;
            cnt += (v != 0.f) ? 1.f : 0.f;
        }
        float pooled = acc / (cnt + 1e-9f);
        float sq = pooled * pooled;
#pragma unroll
        for (int off = 32; off >= 1; off >>= 1) sq += __shfl_xor(sq, off);
        if ((d & 63) == 0) s_w[d >> 6] = sq;
        __syncthreads();
        float tot = s_w[0] + s_w[1];
        float vn = pooled * rsqrtf(tot + 1e-12f);
        __hip_bfloat16 h = __float2bfloat16(vn);
        pnh[c * D_SZ + d] = h;
        pnl[c * D_SZ + d] = __float2bfloat16(vn - __bfloat162float(h));
    }
}

// Fused: rows 0..2047 = en @ en^T -> sim ; rows 2048..4095 = pn @ en^T -> cosm.
// 64x64 tile, 4 waves (2x2 of 32x32), split-bf16 3-term MFMA, XOR-swizzled LDS.
__global__ __launch_bounds__(256) void k_gemm_mfma(const __hip_bfloat16* __restrict__ enh_p,
                                                   const __hip_bfloat16* __restrict__ enl_p,
                                                   const __hip_bfloat16* __restrict__ pnh_p,
                                                   const __hip_bfloat16* __restrict__ pnl_p,
                                                   float* __restrict__ sim,
                                                   float* __restrict__ cosm) {
    extern __shared__ char smem[];
    char* As = smem;           // 64 rows * 512B: kbyte 0..255 = hi, 256..511 = lo
    char* Bs = smem + 32768;
    const int tid = threadIdx.x;
    const __hip_bfloat16* Ah;
    const __hip_bfloat16* Al;
    float* Out;
    int rb;
    if (blockIdx.y < 32) { Ah = enh_p; Al = enl_p; Out = sim;  rb = blockIdx.y << 6; }
    else                 { Ah = pnh_p; Al = pnl_p; Out = cosm; rb = (blockIdx.y - 32) << 6; }
    const int cb = blockIdx.x << 6;
    {
        int r = tid >> 2;
        int c0 = (tid & 3) << 5;
        int sw = (r & 7) << 4;
#pragma unroll
        for (int j = 0; j < 4; ++j) {
            int c = c0 + (j << 3);
            uint4 vh = *(const uint4*)&Ah[(rb + r) * D_SZ + c];
            *(uint4*)(As + r * 512 + ((2 * c) ^ sw)) = vh;
            uint4 vl = *(const uint4*)&Al[(rb + r) * D_SZ + c];
            *(uint4*)(As + r * 512 + ((512 + 2 * c) ^ sw) - 256) = vl;
            uint4 wh = *(const uint4*)&enh_p[(cb + r) * D_SZ + c];
            *(uint4*)(Bs + r * 512 + ((2 * c) ^ sw)) = wh;
            uint4 wl = *(const uint4*)&enl_p[(cb + r) * D_SZ + c];
            *(uint4*)(Bs + r * 512 + ((512 + 2 * c) ^ sw) - 256) = wl;
        }
    }
    __syncthreads();
    const int w = tid >> 6, lane = tid & 63;
    const int wr = (w >> 1) << 5;
    const int wc = (w & 1) << 5;
    const int lrow = lane & 15;
    const int lk = (lane >> 4) << 4;
    int ar0 = wr + lrow, ar1 = wr + 16 + lrow;
    int br0 = wc + lrow, br1 = wc + 16 + lrow;
    const char* pa0 = As + ar0 * 512; const int swa0 = (ar0 & 7) << 4;
    const char* pa1 = As + ar1 * 512; const int swa1 = (ar1 & 7) << 4;
    const char* pb0 = Bs + br0 * 512; const int swb0 = (br0 & 7) << 4;
    const char* pb1 = Bs + br1 * 512; const int swb1 = (br1 & 7) << 4;
    f32x4 acc00 = {0.f, 0.f, 0.f, 0.f};
    f32x4 acc01 = acc00, acc10 = acc00, acc11 = acc00;
#pragma unroll
    for (int term = 0; term < 3; ++term) {
        const int ao = (term == 2) ? 256 : 0;   // A: hi,hi,lo
        const int bo = (term == 1) ? 256 : 0;   // B: hi,lo,hi
#pragma unroll
        for (int kk = 0; kk < 4; ++kk) {
            const int ka = ao + (kk << 6) + lk;
            const int kb = bo + (kk << 6) + lk;
            short8 a0 = *(const short8*)(pa0 + ((ka & 0x100) | ((ka & 0xFF) ^ swa0)));
            short8 a1 = *(const short8*)(pa1 + ((ka & 0x100) | ((ka & 0xFF) ^ swa1)));
            short8 b0 = *(const short8*)(pb0 + ((kb & 0x100) | ((kb & 0xFF) ^ swb0)));
            short8 b1 = *(const short8*)(pb1 + ((kb & 0x100) | ((kb & 0xFF) ^ swb1)));
            acc00 = __builtin_amdgcn_mfma_f32_16x16x32_bf16(a0, b0, acc00, 0, 0, 0);
            acc01 = __builtin_amdgcn_mfma_f32_16x16x32_bf16(a0, b1, acc01, 0, 0, 0);
            acc10 = __builtin_amdgcn_mfma_f32_16x16x32_bf16(a1, b0, acc10, 0, 0, 0);
            acc11 = __builtin_amdgcn_mfma_f32_16x16x32_bf16(a1, b1, acc11, 0, 0, 0);
        }
    }
    const int crow = rb + wr + ((lane >> 4) << 2);
    const int ccol = cb + wc + lrow;
#pragma unroll
    for (int r = 0; r < 4; ++r) {
        Out[(crow + r) * C_SZ + ccol]           = acc00[r];
        Out[(crow + r) * C_SZ + ccol + 16]      = acc01[r];
        Out[(crow + 16 + r) * C_SZ + ccol]      = acc10[r];
        Out[(crow + 16 + r) * C_SZ + ccol + 16] = acc11[r];
    }
}

// Single-pass bucket-rank: value-linear 2048-bucket histogram -> scan -> scatter
// (key,idx) u64 pairs -> rank = bucket_start + #{bucket-mates < mine} (exact,
// stable) -> discounted logits -> log_softmax -> diagonal -> loss.
__global__ __launch_bounds__(256) void k_rank_softmax(const float* __restrict__ sim,
                                                      const float* __restrict__ cosm,
                                                      const int* __restrict__ pos_count,
                                                      const float* __restrict__ tab,
                                                      float* __restrict__ acc) {
    int i = blockIdx.x;
    if (pos_count[i] == 0) return;
    __shared__ unsigned long long s_pairs[C_SZ];  // 16 KB
    __shared__ unsigned s_hist[C_SZ];             // 8 KB
    __shared__ int s_wt[4];
    __shared__ float s_red[4];
    __shared__ float s_diag;
    const int tid = threadIdx.x;
    const int lane = tid & 63;
    const int w = tid >> 6;
    const int base = tid << 3;

    float4 sa = *(const float4*)&sim[i * C_SZ + base];
    float4 sb = *(const float4*)&sim[i * C_SZ + base + 4];
    float4 ca = *(const float4*)&cosm[i * C_SZ + base];
    float4 cb = *(const float4*)&cosm[i * C_SZ + base + 4];
    uint4 z4 = {0u, 0u, 0u, 0u};
    ((uint4*)s_hist)[tid] = z4;
    ((uint4*)s_hist)[tid + 256] = z4;

    float xs[8] = {sa.x, sa.y, sa.z, sa.w, sb.x, sb.y, sb.z, sb.w};
    unsigned uk[8];
    int bk[8];
#pragma unroll
    for (int e = 0; e < 8; ++e) {
        unsigned u = __float_as_uint(xs[e]);
        u = (u & 0x80000000u) ? ~u : (u | 0x80000000u);
        if (u == 0x7FFFFFFFu) u = 0x80000000u;   // -0.0 == +0.0
        uk[e] = u;
        int b = (int)((xs[e] + 1.0f) * 1023.5f);
        bk[e] = b < 0 ? 0 : (b > 2047 ? 2047 : b);
    }
    __syncthreads();
#pragma unroll
    for (int e = 0; e < 8; ++e) atomicAdd(&s_hist[bk[e]], 1u);
    __syncthreads();
    // exclusive scan of 2048 counts (8 contiguous per thread)
    uint4 h0 = ((const uint4*)s_hist)[2 * tid];
    uint4 h1 = ((const uint4*)s_hist)[2 * tid + 1];
    unsigned hv[8] = {h0.x, h0.y, h0.z, h0.w, h1.x, h1.y, h1.z, h1.w};
    unsigned excl[8];
    unsigned sum = 0;
#pragma unroll
    for (int j = 0; j < 8; ++j) { excl[j] = sum; sum += hv[j]; }
    int incl = (int)sum;
#pragma unroll
    for (int off = 1; off < 64; off <<= 1) {
        int o = __shfl_up(incl, off);
        if (lane >= off) incl += o;
    }
    if (lane == 63) s_wt[w] = incl;
    __syncthreads();
    int wbase = 0;
#pragma unroll
    for (int ww = 0; ww < 4; ++ww) wbase += (ww < w) ? s_wt[ww] : 0;
    unsigned ebase = (unsigned)(wbase + incl - (int)sum);
    uint4 w0 = {excl[0] + ebase, excl[1] + ebase, excl[2] + ebase, excl[3] + ebase};
    uint4 w1 = {excl[4] + ebase, excl[5] + ebase, excl[6] + ebase, excl[7] + ebase};
    ((uint4*)s_hist)[2 * tid] = w0;
    ((uint4*)s_hist)[2 * tid + 1] = w1;
    __syncthreads();
    // scatter pairs grouped by bucket (intra-bucket order irrelevant)
    unsigned long long mypair[8];
#pragma unroll
    for (int e = 0; e < 8; ++e) {
        unsigned long long pr = ((unsigned long long)uk[e] << 32) | (unsigned)(base + e);
        mypair[e] = pr;
        unsigned pos = atomicAdd(&s_hist[bk[e]], 1u);
        s_pairs[pos] = pr;
    }
    __syncthreads();
    // ranks: post-scatter s_hist[b] == end[b]; start[b] = b ? s_hist[b-1] : 0
    int rk[8];
#pragma unroll
    for (int e = 0; e < 8; ++e) {
        int b = bk[e];
        int end = (int)s_hist[b];
        int start = b ? (int)s_hist[b - 1] : 0;
        unsigned long long me = mypair[e];
        int cnt = 0;
        for (int j = start; j < end; ++j) cnt += (s_pairs[j] < me) ? 1 : 0;
        rk[e] = start + cnt;
    }
    float cs[8] = {ca.x, ca.y, ca.z, ca.w, cb.x, cb.y, cb.z, cb.w};
    float lg[8];
    float lmax = -3.4e38f;
#pragma unroll
    for (int e = 0; e < 8; ++e) {
        lg[e] = cs[e] * tab[rk[e]];
        lmax = fmaxf(lmax, lg[e]);
    }
    if ((i >> 3) == tid) {
        int ei = i & 7;
        float dv = lg[0];
#pragma unroll
        for (int e = 1; e < 8; ++e) dv = (ei == e) ? lg[e] : dv;
        s_diag = dv;
    }
#pragma unroll
    for (int off = 1; off < 64; off <<= 1) lmax = fmaxf(lmax, __shfl_xor(lmax, off));
    if (lane == 0) s_red[w] = lmax;
    __syncthreads();
    float m = fmaxf(fmaxf(s_red[0], s_red[1]), fmaxf(s_red[2], s_red[3]));
    float lsum = 0.f;
#pragma unroll
    for (int e = 0; e < 8; ++e) lsum += __expf(lg[e] - m);
#pragma unroll
    for (int off = 1; off < 64; off <<= 1) lsum += __shfl_xor(lsum, off);
    __syncthreads();
    if (lane == 0) s_red[w] = lsum;
    __syncthreads();
    if (tid == 0) {
        float tot = s_red[0] + s_red[1] + s_red[2] + s_red[3];
        float pos_lp = s_diag - m - logf(tot);
        atomicAdd(&acc[0], -pos_lp);
        atomicAdd(&acc[1], 1.0f);
    }
}

__global__ void k_final(const float* __restrict__ acc, float* __restrict__ out) {
    out[0] = acc[0] / fmaxf(acc[1], 1.0f);
}

extern "C" void kernel_launch(void* const* d_in, const int* in_sizes, int n_in,
                              void* d_out, int out_size, void* d_ws, size_t ws_size,
                              hipStream_t stream) {
    const float* output    = (const float*)d_in[0];
    const float* class_emb = (const float*)d_in[1];
    const float* targets   = (const float*)d_in[2];
    const float* tempPtr   = (const float*)d_in[3];
    float* out = (float*)d_out;
    char* ws = (char*)d_ws;

    int*   pos_count = (int*)(ws + 0);
    float* acc       = (float*)(ws + 8192);
    int*   pos_list  = (int*)(ws + 8448);
    __hip_bfloat16* pnh = (__hip_bfloat16*)(ws + 2105600);
    __hip_bfloat16* pnl = (__hip_bfloat16*)(ws + 2629888);
    __hip_bfloat16* enh = (__hip_bfloat16*)(ws + 3154176);
    __hip_bfloat16* enl = (__hip_bfloat16*)(ws + 3678464);
    float* tab       = (float*)(ws + 4202752);
    float* sim       = (float*)(ws + 4210944);
    float* cosm      = (float*)(ws + 20988160);

    hipMemsetAsync(ws, 0, 8448, stream);

    k_scan<<<4096, 256, 0, stream>>>(targets, pos_count, pos_list);
    k_poolnorm<<<2 * C_SZ, 128, 0, stream>>>(output, class_emb, tempPtr, pos_count,
                                             pos_list, pnh, pnl, enh, enl, tab);
    dim3 g(C_SZ / 64, 2 * C_SZ / 64);
    k_gemm_mfma<<<g, 256, 65536, stream>>>(enh, enl, pnh, pnl, sim, cosm);
    k_rank_softmax<<<C_SZ, 256, 0, stream>>>(sim, cosm, pos_count, tab, acc);
    k_final<<<1, 1, 0, stream>>>(acc, out);
}

// Round 5
// 140.589 us; speedup vs baseline: 2.2370x; 1.0021x over previous
//
#include <hip/hip_runtime.h>
#include <hip/hip_bf16.h>
#include <math.h>

#define B_SZ 16384
#define C_SZ 2048
#define D_SZ 128
#define MAXP 256

typedef float f32x4 __attribute__((ext_vector_type(4)));
typedef short short8 __attribute__((ext_vector_type(8)));

// ---- workspace layout (bytes) ----
// 0        : pos_count[C]     int   (8192)
// 8192     : acc[2]           float (8)
// 8448     : pos_list[C*MAXP] int   (2 MB)   -> 2,105,600
// 2105600  : pnh [C*D] bf16 (512KB) -> 2,629,888
// 2629888  : pnl [C*D] bf16 (512KB) -> 3,154,176
// 3154176  : enh [C*D] bf16 (512KB) -> 3,678,464
// 3678464  : enl [C*D] bf16 (512KB) -> 4,202,752
// 4202752  : tab[C] f32 (8KB)       -> 4,210,944
// 4210944  : sim[C*C] f32 (16MB)    -> 20,988,160
// 20988160 : cosm[C*C] f32 (16MB)   -> 37,765,376

// zero pos_count[2048] + acc[2] (2112 dwords) — replaces pathological 75us fill node
__global__ __launch_bounds__(256) void k_zero(unsigned* __restrict__ p) {
    int t = blockIdx.x * blockDim.x + threadIdx.x;
    if (t < 2112) p[t] = 0u;
}

__global__ __launch_bounds__(256) void k_scan(const float* __restrict__ targets,
                                              int* __restrict__ pos_count,
                                              int* __restrict__ pos_list) {
    int tid = blockIdx.x * blockDim.x + threadIdx.x;
    int total = (B_SZ * C_SZ) >> 2;
    int stride = gridDim.x * blockDim.x;
    for (int v = tid; v < total; v += stride) {
        float4 t = ((const float4*)targets)[v];
        if (t.x != 0.f || t.y != 0.f || t.z != 0.f || t.w != 0.f) {
            int e0 = v << 2;
            int b = e0 >> 11;
            int c0 = e0 & (C_SZ - 1);
            float vals[4] = {t.x, t.y, t.z, t.w};
#pragma unroll
            for (int q = 0; q < 4; ++q) {
                if (vals[q] != 0.f) {
                    int c = c0 + q;
                    int slot = atomicAdd(&pos_count[c], 1);
                    if (slot < MAXP) pos_list[c * MAXP + slot] = b;
                }
            }
        }
    }
}

// blocks 0..2047: L2-normalize class_emb -> en(h,l) + tab; blocks 2048..4095: pool -> pn(h,l)
__global__ __launch_bounds__(128) void k_poolnorm(const float* __restrict__ output,
                                                  const float* __restrict__ class_emb,
                                                  const float* __restrict__ tempPtr,
                                                  const int* __restrict__ pos_count,
                                                  const int* __restrict__ pos_list,
                                                  __hip_bfloat16* __restrict__ pnh,
                                                  __hip_bfloat16* __restrict__ pnl,
                                                  __hip_bfloat16* __restrict__ enh,
                                                  __hip_bfloat16* __restrict__ enl,
                                                  float* __restrict__ tab) {
    int d = threadIdx.x;
    __shared__ float s_w[2];
    if (blockIdx.x < C_SZ) {
        int c = blockIdx.x;
        float v = class_emb[c * D_SZ + d];
        float sq = v * v;
#pragma unroll
        for (int off = 32; off >= 1; off >>= 1) sq += __shfl_xor(sq, off);
        if ((d & 63) == 0) s_w[d >> 6] = sq;
        __syncthreads();
        float tot = s_w[0] + s_w[1];
        float vn = v * rsqrtf(tot + 1e-12f);
        __hip_bfloat16 h = __float2bfloat16(vn);
        enh[c * D_SZ + d] = h;
        enl[c * D_SZ + d] = __float2bfloat16(vn - __bfloat162float(h));
        if (d == 0) tab[c] = 1.0f / (tempPtr[0] * logf((float)c + 2.0f));
    } else {
        int c = blockIdx.x - C_SZ;
        int n = pos_count[c];
        if (n > MAXP) n = MAXP;
        float acc = 0.f, cnt = 0.f;
        for (int k = 0; k < n; ++k) {
            int b = pos_list[c * MAXP + k];
            float v = output[b * D_SZ + d];
            acc += v;
            cnt += (v != 0.f) ? 1.f : 0.f;
        }
        float pooled = acc / (cnt + 1e-9f);
        float sq = pooled * pooled;
#pragma unroll
        for (int off = 32; off >= 1; off >>= 1) sq += __shfl_xor(sq, off);
        if ((d & 63) == 0) s_w[d >> 6] = sq;
        __syncthreads();
        float tot = s_w[0] + s_w[1];
        float vn = pooled * rsqrtf(tot + 1e-12f);
        __hip_bfloat16 h = __float2bfloat16(vn);
        pnh[c * D_SZ + d] = h;
        pnl[c * D_SZ + d] = __float2bfloat16(vn - __bfloat162float(h));
    }
}

// Fused: rows 0..2047 = en @ en^T -> sim ; rows 2048..4095 = pn @ en^T -> cosm.
// 64x64 tile, 4 waves (2x2 of 32x32), split-bf16 3-term MFMA, XOR-swizzled LDS.
__global__ __launch_bounds__(256) void k_gemm_mfma(const __hip_bfloat16* __restrict__ enh_p,
                                                   const __hip_bfloat16* __restrict__ enl_p,
                                                   const __hip_bfloat16* __restrict__ pnh_p,
                                                   const __hip_bfloat16* __restrict__ pnl_p,
                                                   float* __restrict__ sim,
                                                   float* __restrict__ cosm) {
    extern __shared__ char smem[];
    char* As = smem;           // 64 rows * 512B: kbyte 0..255 = hi, 256..511 = lo
    char* Bs = smem + 32768;
    const int tid = threadIdx.x;
    const __hip_bfloat16* Ah;
    const __hip_bfloat16* Al;
    float* Out;
    int rb;
    if (blockIdx.y < 32) { Ah = enh_p; Al = enl_p; Out = sim;  rb = blockIdx.y << 6; }
    else                 { Ah = pnh_p; Al = pnl_p; Out = cosm; rb = (blockIdx.y - 32) << 6; }
    const int cb = blockIdx.x << 6;
    {
        int r = tid >> 2;
        int c0 = (tid & 3) << 5;
        int sw = (r & 7) << 4;
#pragma unroll
        for (int j = 0; j < 4; ++j) {
            int c = c0 + (j << 3);
            uint4 vh = *(const uint4*)&Ah[(rb + r) * D_SZ + c];
            *(uint4*)(As + r * 512 + ((2 * c) ^ sw)) = vh;
            uint4 vl = *(const uint4*)&Al[(rb + r) * D_SZ + c];
            *(uint4*)(As + r * 512 + ((512 + 2 * c) ^ sw) - 256) = vl;
            uint4 wh = *(const uint4*)&enh_p[(cb + r) * D_SZ + c];
            *(uint4*)(Bs + r * 512 + ((2 * c) ^ sw)) = wh;
            uint4 wl = *(const uint4*)&enl_p[(cb + r) * D_SZ + c];
            *(uint4*)(Bs + r * 512 + ((512 + 2 * c) ^ sw) - 256) = wl;
        }
    }
    __syncthreads();
    const int w = tid >> 6, lane = tid & 63;
    const int wr = (w >> 1) << 5;
    const int wc = (w & 1) << 5;
    const int lrow = lane & 15;
    const int lk = (lane >> 4) << 4;
    int ar0 = wr + lrow, ar1 = wr + 16 + lrow;
    int br0 = wc + lrow, br1 = wc + 16 + lrow;
    const char* pa0 = As + ar0 * 512; const int swa0 = (ar0 & 7) << 4;
    const char* pa1 = As + ar1 * 512; const int swa1 = (ar1 & 7) << 4;
    const char* pb0 = Bs + br0 * 512; const int swb0 = (br0 & 7) << 4;
    const char* pb1 = Bs + br1 * 512; const int swb1 = (br1 & 7) << 4;
    f32x4 acc00 = {0.f, 0.f, 0.f, 0.f};
    f32x4 acc01 = acc00, acc10 = acc00, acc11 = acc00;
#pragma unroll
    for (int term = 0; term < 3; ++term) {
        const int ao = (term == 2) ? 256 : 0;   // A: hi,hi,lo
        const int bo = (term == 1) ? 256 : 0;   // B: hi,lo,hi
#pragma unroll
        for (int kk = 0; kk < 4; ++kk) {
            const int ka = ao + (kk << 6) + lk;
            const int kb = bo + (kk << 6) + lk;
            short8 a0 = *(const short8*)(pa0 + ((ka & 0x100) | ((ka & 0xFF) ^ swa0)));
            short8 a1 = *(const short8*)(pa1 + ((ka & 0x100) | ((ka & 0xFF) ^ swa1)));
            short8 b0 = *(const short8*)(pb0 + ((kb & 0x100) | ((kb & 0xFF) ^ swb0)));
            short8 b1 = *(const short8*)(pb1 + ((kb & 0x100) | ((kb & 0xFF) ^ swb1)));
            acc00 = __builtin_amdgcn_mfma_f32_16x16x32_bf16(a0, b0, acc00, 0, 0, 0);
            acc01 = __builtin_amdgcn_mfma_f32_16x16x32_bf16(a0, b1, acc01, 0, 0, 0);
            acc10 = __builtin_amdgcn_mfma_f32_16x16x32_bf16(a1, b0, acc10, 0, 0, 0);
            acc11 = __builtin_amdgcn_mfma_f32_16x16x32_bf16(a1, b1, acc11, 0, 0, 0);
        }
    }
    const int crow = rb + wr + ((lane >> 4) << 2);
    const int ccol = cb + wc + lrow;
#pragma unroll
    for (int r = 0; r < 4; ++r) {
        Out[(crow + r) * C_SZ + ccol]           = acc00[r];
        Out[(crow + r) * C_SZ + ccol + 16]      = acc01[r];
        Out[(crow + 16 + r) * C_SZ + ccol]      = acc10[r];
        Out[(crow + 16 + r) * C_SZ + ccol + 16] = acc11[r];
    }
}

// Single-pass bucket-rank: value-linear 2048-bucket histogram -> scan -> scatter
// (key,idx) u64 pairs -> rank = bucket_start + #{bucket-mates < mine} (exact,
// stable) -> discounted logits -> log_softmax -> diagonal -> loss.
__global__ __launch_bounds__(256) void k_rank_softmax(const float* __restrict__ sim,
                                                      const float* __restrict__ cosm,
                                                      const int* __restrict__ pos_count,
                                                      const float* __restrict__ tab,
                                                      float* __restrict__ acc) {
    int i = blockIdx.x;
    if (pos_count[i] == 0) return;
    __shared__ unsigned long long s_pairs[C_SZ];  // 16 KB
    __shared__ unsigned s_hist[C_SZ];             // 8 KB
    __shared__ int s_wt[4];
    __shared__ float s_red[4];
    __shared__ float s_diag;
    const int tid = threadIdx.x;
    const int lane = tid & 63;
    const int w = tid >> 6;
    const int base = tid << 3;

    float4 sa = *(const float4*)&sim[i * C_SZ + base];
    float4 sb = *(const float4*)&sim[i * C_SZ + base + 4];
    float4 ca = *(const float4*)&cosm[i * C_SZ + base];
    float4 cb = *(const float4*)&cosm[i * C_SZ + base + 4];
    uint4 z4 = {0u, 0u, 0u, 0u};
    ((uint4*)s_hist)[tid] = z4;
    ((uint4*)s_hist)[tid + 256] = z4;

    float xs[8] = {sa.x, sa.y, sa.z, sa.w, sb.x, sb.y, sb.z, sb.w};
    unsigned uk[8];
    int bk[8];
#pragma unroll
    for (int e = 0; e < 8; ++e) {
        unsigned u = __float_as_uint(xs[e]);
        u = (u & 0x80000000u) ? ~u : (u | 0x80000000u);
        if (u == 0x7FFFFFFFu) u = 0x80000000u;   // -0.0 == +0.0
        uk[e] = u;
        int b = (int)((xs[e] + 1.0f) * 1023.5f);
        bk[e] = b < 0 ? 0 : (b > 2047 ? 2047 : b);
    }
    __syncthreads();
#pragma unroll
    for (int e = 0; e < 8; ++e) atomicAdd(&s_hist[bk[e]], 1u);
    __syncthreads();
    // exclusive scan of 2048 counts (8 contiguous per thread)
    uint4 h0 = ((const uint4*)s_hist)[2 * tid];
    uint4 h1 = ((const uint4*)s_hist)[2 * tid + 1];
    unsigned hv[8] = {h0.x, h0.y, h0.z, h0.w, h1.x, h1.y, h1.z, h1.w};
    unsigned excl[8];
    unsigned sum = 0;
#pragma unroll
    for (int j = 0; j < 8; ++j) { excl[j] = sum; sum += hv[j]; }
    int incl = (int)sum;
#pragma unroll
    for (int off = 1; off < 64; off <<= 1) {
        int o = __shfl_up(incl, off);
        if (lane >= off) incl += o;
    }
    if (lane == 63) s_wt[w] = incl;
    __syncthreads();
    int wbase = 0;
#pragma unroll
    for (int ww = 0; ww < 4; ++ww) wbase += (ww < w) ? s_wt[ww] : 0;
    unsigned ebase = (unsigned)(wbase + incl - (int)sum);
    uint4 w0 = {excl[0] + ebase, excl[1] + ebase, excl[2] + ebase, excl[3] + ebase};
    uint4 w1 = {excl[4] + ebase, excl[5] + ebase, excl[6] + ebase, excl[7] + ebase};
    ((uint4*)s_hist)[2 * tid] = w0;
    ((uint4*)s_hist)[2 * tid + 1] = w1;
    __syncthreads();
    // scatter pairs grouped by bucket (intra-bucket order irrelevant)
    unsigned long long mypair[8];
#pragma unroll
    for (int e = 0; e < 8; ++e) {
        unsigned long long pr = ((unsigned long long)uk[e] << 32) | (unsigned)(base + e);
        mypair[e] = pr;
        unsigned pos = atomicAdd(&s_hist[bk[e]], 1u);
        s_pairs[pos] = pr;
    }
    __syncthreads();
    // ranks: post-scatter s_hist[b] == end[b]; start[b] = b ? s_hist[b-1] : 0
    int rk[8];
#pragma unroll
    for (int e = 0; e < 8; ++e) {
        int b = bk[e];
        int end = (int)s_hist[b];
        int start = b ? (int)s_hist[b - 1] : 0;
        unsigned long long me = mypair[e];
        int cnt = 0;
        for (int j = start; j < end; ++j) cnt += (s_pairs[j] < me) ? 1 : 0;
        rk[e] = start + cnt;
    }
    float cs[8] = {ca.x, ca.y, ca.z, ca.w, cb.x, cb.y, cb.z, cb.w};
    float lg[8];
    float lmax = -3.4e38f;
#pragma unroll
    for (int e = 0; e < 8; ++e) {
        lg[e] = cs[e] * tab[rk[e]];
        lmax = fmaxf(lmax, lg[e]);
    }
    if ((i >> 3) == tid) {
        int ei = i & 7;
        float dv = lg[0];
#pragma unroll
        for (int e = 1; e < 8; ++e) dv = (ei == e) ? lg[e] : dv;
        s_diag = dv;
    }
#pragma unroll
    for (int off = 1; off < 64; off <<= 1) lmax = fmaxf(lmax, __shfl_xor(lmax, off));
    if (lane == 0) s_red[w] = lmax;
    __syncthreads();
    float m = fmaxf(fmaxf(s_red[0], s_red[1]), fmaxf(s_red[2], s_red[3]));
    float lsum = 0.f;
#pragma unroll
    for (int e = 0; e < 8; ++e) lsum += __expf(lg[e] - m);
#pragma unroll
    for (int off = 1; off < 64; off <<= 1) lsum += __shfl_xor(lsum, off);
    __syncthreads();
    if (lane == 0) s_red[w] = lsum;
    __syncthreads();
    if (tid == 0) {
        float tot = s_red[0] + s_red[1] + s_red[2] + s_red[3];
        float pos_lp = s_diag - m - logf(tot);
        atomicAdd(&acc[0], -pos_lp);
        atomicAdd(&acc[1], 1.0f);
    }
}

__global__ void k_final(const float* __restrict__ acc, float* __restrict__ out) {
    out[0] = acc[0] / fmaxf(acc[1], 1.0f);
}

extern "C" void kernel_launch(void* const* d_in, const int* in_sizes, int n_in,
                              void* d_out, int out_size, void* d_ws, size_t ws_size,
                              hipStream_t stream) {
    const float* output    = (const float*)d_in[0];
    const float* class_emb = (const float*)d_in[1];
    const float* targets   = (const float*)d_in[2];
    const float* tempPtr   = (const float*)d_in[3];
    float* out = (float*)d_out;
    char* ws = (char*)d_ws;

    int*   pos_count = (int*)(ws + 0);
    float* acc       = (float*)(ws + 8192);
    int*   pos_list  = (int*)(ws + 8448);
    __hip_bfloat16* pnh = (__hip_bfloat16*)(ws + 2105600);
    __hip_bfloat16* pnl = (__hip_bfloat16*)(ws + 2629888);
    __hip_bfloat16* enh = (__hip_bfloat16*)(ws + 3154176);
    __hip_bfloat16* enl = (__hip_bfloat16*)(ws + 3678464);
    float* tab       = (float*)(ws + 4202752);
    float* sim       = (float*)(ws + 4210944);
    float* cosm      = (float*)(ws + 20988160);

    k_zero<<<9, 256, 0, stream>>>((unsigned*)ws);
    k_scan<<<4096, 256, 0, stream>>>(targets, pos_count, pos_list);
    k_poolnorm<<<2 * C_SZ, 128, 0, stream>>>(output, class_emb, tempPtr, pos_count,
                                             pos_list, pnh, pnl, enh, enl, tab);
    dim3 g(C_SZ / 64, 2 * C_SZ / 64);
    k_gemm_mfma<<<g, 256, 65536, stream>>>(enh, enl, pnh, pnl, sim, cosm);
    k_rank_softmax<<<C_SZ, 256, 0, stream>>>(sim, cosm, pos_count, tab, acc);
    k_final<<<1, 1, 0, stream>>>(acc, out);
}